// Round 1
// baseline (1036.150 us; speedup 1.0000x reference)
//
#include <hip/hip_runtime.h>
#include <math.h>

#define NL 4
#define DIM 512
#define NH 32
#define DHD 16
#define SEQ 1024
#define NB 2
#define LN_EPS 1e-5f
#define NEGF (-1e30f)

__device__ __forceinline__ float gelu_exact(float x) {
    return 0.5f * x * (1.0f + erff(x * 0.70710678118654752f));
}

// ---------------------------------------------------------------- init: h = gelu(x*Winit + binit)
__global__ __launch_bounds__(256) void k_init(const float* __restrict__ x,
        const float* __restrict__ Wi, const float* __restrict__ bi,
        float* __restrict__ h) {
    int idx = blockIdx.x * 256 + threadIdx.x;
    int d = idx & (DIM - 1);
    int bs = idx >> 9;                 // /DIM
    h[idx] = gelu_exact(x[bs] * Wi[d] + bi[d]);
}

// ---------------------------------------------------------------- fp32 tiled GEMM 64x64, BK=16
__device__ __forceinline__ void gemm_tile(const float* __restrict__ A,
        const float* __restrict__ W, const float* __restrict__ bias,
        float* __restrict__ C, int m0, int n0) {
    __shared__ float As[16][68];
    __shared__ float Bs[16][68];
    int tid = threadIdx.x;
    int tx = tid & 15, ty = tid >> 4;
    int arow = tid >> 2, acg = (tid & 3) << 2;
    int brow = tid >> 4, bcg = (tid & 15) << 2;
    float acc[4][4] = {{0.f}};
    for (int k0 = 0; k0 < DIM; k0 += 16) {
        float4 av = *(const float4*)(A + (size_t)(m0 + arow) * DIM + k0 + acg);
        float4 bv = *(const float4*)(W + (size_t)(k0 + brow) * DIM + n0 + bcg);
        As[acg + 0][arow] = av.x;
        As[acg + 1][arow] = av.y;
        As[acg + 2][arow] = av.z;
        As[acg + 3][arow] = av.w;
        *(float4*)&Bs[brow][bcg] = bv;
        __syncthreads();
        #pragma unroll
        for (int kk = 0; kk < 16; kk++) {
            float4 a4 = *(const float4*)&As[kk][ty << 2];
            float4 b4 = *(const float4*)&Bs[kk][tx << 2];
            float aa[4] = {a4.x, a4.y, a4.z, a4.w};
            float bb[4] = {b4.x, b4.y, b4.z, b4.w};
            #pragma unroll
            for (int i = 0; i < 4; i++)
                #pragma unroll
                for (int j = 0; j < 4; j++)
                    acc[i][j] = fmaf(aa[i], bb[j], acc[i][j]);
        }
        __syncthreads();
    }
    float bb4[4];
    #pragma unroll
    for (int j = 0; j < 4; j++) bb4[j] = bias[n0 + (tx << 2) + j];
    #pragma unroll
    for (int i = 0; i < 4; i++) {
        float4 r;
        r.x = acc[i][0] + bb4[0];
        r.y = acc[i][1] + bb4[1];
        r.z = acc[i][2] + bb4[2];
        r.w = acc[i][3] + bb4[3];
        *(float4*)(C + (size_t)(m0 + (ty << 2) + i) * DIM + n0 + (tx << 2)) = r;
    }
}

__global__ __launch_bounds__(256) void k_gemm_qkv(const float* __restrict__ h,
        const float* __restrict__ Wq, const float* __restrict__ bq,
        const float* __restrict__ Wk, const float* __restrict__ bk,
        const float* __restrict__ Wv, const float* __restrict__ bv,
        float* __restrict__ q, float* __restrict__ k, float* __restrict__ v) {
    int which = blockIdx.y >> 3;       // 0=q 1=k 2=v
    int nb = blockIdx.y & 7;
    const float* W = (which == 0) ? Wq : (which == 1) ? Wk : Wv;
    const float* bias = (which == 0) ? bq : (which == 1) ? bk : bv;
    float* C = (which == 0) ? q : (which == 1) ? k : v;
    gemm_tile(h, W, bias, C, blockIdx.x * 64, nb * 64);
}

__global__ __launch_bounds__(256) void k_gemm_one(const float* __restrict__ A,
        const float* __restrict__ W, const float* __restrict__ bias,
        float* __restrict__ C) {
    gemm_tile(A, W, bias, C, blockIdx.x * 64, blockIdx.y * 64);
}

// ---------------------------------------------------------------- causal rel-pos attention
// grid (B*H, S/64), block 256. thread = (row 0..63, sub 0..3); sub strides cols mod 4.
// scores[s,t] = q[s]·(k[t] + Er[1023-s+t]) * 0.25, t<=s. online softmax per thread, merged over subs.
__global__ __launch_bounds__(256) void k_attn(const float* __restrict__ q,
        const float* __restrict__ k, const float* __restrict__ v,
        const float* __restrict__ Er, float* __restrict__ aout) {
    __shared__ float Kt[128][20];   // pad 16->20: breaks 64B-stride write conflicts
    __shared__ float Vt[128][20];
    int bh = blockIdx.x;
    int b_ = bh >> 5, h_ = bh & 31;
    int r0 = blockIdx.y << 6;
    int tid = threadIdx.x;
    int row = tid >> 2, sub = tid & 3;
    int s = r0 + row;
    const float* qp = q + ((size_t)(b_ * SEQ + s)) * DIM + h_ * DHD;
    float4 q0 = *(const float4*)(qp);
    float4 q1 = *(const float4*)(qp + 4);
    float4 q2 = *(const float4*)(qp + 8);
    float4 q3 = *(const float4*)(qp + 12);
    float m = NEGF, l = 0.f;
    float o[16];
    #pragma unroll
    for (int i = 0; i < 16; i++) o[i] = 0.f;
    int tmax = r0 + 64;
    for (int ct = 0; ct < tmax; ct += 128) {
        // stage K rows (waves 0-1) and V rows (waves 2-3): always in-bounds (ct+127 <= 1023)
        {
            int i = tid & 127;
            const float* src = ((tid < 128) ? k : v)
                               + ((size_t)(b_ * SEQ + ct + i)) * DIM + h_ * DHD;
            float* dst = (tid < 128) ? &Kt[i][0] : &Vt[i][0];
            *(float4*)(dst + 0)  = *(const float4*)(src + 0);
            *(float4*)(dst + 4)  = *(const float4*)(src + 4);
            *(float4*)(dst + 8)  = *(const float4*)(src + 8);
            *(float4*)(dst + 12) = *(const float4*)(src + 12);
        }
        __syncthreads();
        for (int i0 = 0; i0 < 32; i0 += 8) {
            float sc[8];
            float cmax = NEGF;
            #pragma unroll
            for (int jj = 0; jj < 8; jj++) {
                int tl = ((i0 + jj) << 2) + sub;
                int t = ct + tl;
                int jrow = (SEQ - 1) - s + t;          // >=0 always; clamp upper for masked lanes
                jrow = (jrow < SEQ - 1) ? jrow : (SEQ - 1);
                const float* er = Er + jrow * DHD;
                const float* kr = &Kt[tl][0];
                float4 ka = *(const float4*)(kr);
                float4 kb = *(const float4*)(kr + 4);
                float4 kc = *(const float4*)(kr + 8);
                float4 kd = *(const float4*)(kr + 12);
                float4 ea = *(const float4*)(er);
                float4 eb = *(const float4*)(er + 4);
                float4 ec = *(const float4*)(er + 8);
                float4 ed = *(const float4*)(er + 12);
                float d0 = q0.x*(ka.x+ea.x) + q0.y*(ka.y+ea.y) + q0.z*(ka.z+ea.z) + q0.w*(ka.w+ea.w);
                float d1 = q1.x*(kb.x+eb.x) + q1.y*(kb.y+eb.y) + q1.z*(kb.z+eb.z) + q1.w*(kb.w+eb.w);
                float d2 = q2.x*(kc.x+ec.x) + q2.y*(kc.y+ec.y) + q2.z*(kc.z+ec.z) + q2.w*(kc.w+ec.w);
                float d3 = q3.x*(kd.x+ed.x) + q3.y*(kd.y+ed.y) + q3.z*(kd.z+ed.z) + q3.w*(kd.w+ed.w);
                float sv = ((d0 + d1) + (d2 + d3)) * 0.25f;
                sc[jj] = (t <= s) ? sv : NEGF;
                cmax = fmaxf(cmax, sc[jj]);
            }
            if (cmax == NEGF) continue;                // whole chunk masked
            float nm = fmaxf(m, cmax);
            float alpha = __expf(m - nm);              // m==NEGF -> 0, no NaN
            m = nm;
            l *= alpha;
            #pragma unroll
            for (int i = 0; i < 16; i++) o[i] *= alpha;
            #pragma unroll
            for (int jj = 0; jj < 8; jj++) {
                int tl = ((i0 + jj) << 2) + sub;
                float e = __expf(sc[jj] - m);          // masked -> exp(-1e30)=0
                l += e;
                const float* vr = &Vt[tl][0];
                #pragma unroll
                for (int i = 0; i < 16; i++) o[i] = fmaf(e, vr[i], o[i]);
            }
        }
        __syncthreads();
    }
    // merge the 4 sub-lanes (lanes xor 1, xor 2). NEGF sentinel keeps this NaN-free.
    #pragma unroll
    for (int off = 1; off <= 2; off <<= 1) {
        float om = __shfl_xor(m, off);
        float ol = __shfl_xor(l, off);
        float nm = fmaxf(m, om);
        float a1 = __expf(m - nm);
        float a2 = __expf(om - nm);
        l = l * a1 + ol * a2;
        #pragma unroll
        for (int i = 0; i < 16; i++) {
            float oo = __shfl_xor(o[i], off);
            o[i] = o[i] * a1 + oo * a2;
        }
        m = nm;
    }
    float invl = 1.0f / l;                             // l>0: t=0 always valid for the row
    float4 w;
    if (sub == 0)      w = make_float4(o[0],  o[1],  o[2],  o[3]);
    else if (sub == 1) w = make_float4(o[4],  o[5],  o[6],  o[7]);
    else if (sub == 2) w = make_float4(o[8],  o[9],  o[10], o[11]);
    else               w = make_float4(o[12], o[13], o[14], o[15]);
    w.x *= invl; w.y *= invl; w.z *= invl; w.w *= invl;
    *(float4*)(aout + ((size_t)(b_ * SEQ + s)) * DIM + h_ * DHD + (sub << 2)) = w;
}

// ---------------------------------------------------------------- h += gelu(LN(y))
__global__ __launch_bounds__(256) void k_ln_gelu_res(const float* __restrict__ y,
        const float* __restrict__ gam, const float* __restrict__ bet,
        float* __restrict__ h) {
    __shared__ float red[8];
    int row = blockIdx.x, tid = threadIdx.x;
    const float* yr = y + (size_t)row * DIM;
    float v0 = yr[tid], v1 = yr[tid + 256];
    float sum = v0 + v1, sq = v0 * v0 + v1 * v1;
    #pragma unroll
    for (int off = 32; off > 0; off >>= 1) {
        sum += __shfl_down(sum, off);
        sq  += __shfl_down(sq, off);
    }
    if ((tid & 63) == 0) { red[tid >> 6] = sum; red[4 + (tid >> 6)] = sq; }
    __syncthreads();
    float ts = red[0] + red[1] + red[2] + red[3];
    float tq = red[4] + red[5] + red[6] + red[7];
    float mu = ts * (1.0f / DIM);
    float var = tq * (1.0f / DIM) - mu * mu;
    float rs = rsqrtf(var + LN_EPS);
    float z0 = (v0 - mu) * rs * gam[tid] + bet[tid];
    float z1 = (v1 - mu) * rs * gam[tid + 256] + bet[tid + 256];
    size_t base = (size_t)row * DIM;
    h[base + tid]       += gelu_exact(z0);
    h[base + tid + 256] += gelu_exact(z1);
}

// ---------------------------------------------------------------- final sum over S, dot with Wout
__global__ __launch_bounds__(256) void k_colsum(const float* __restrict__ h,
        float* __restrict__ partial) {
    int bt = blockIdx.x;               // b*16 + stile
    int b_ = bt >> 4, t = bt & 15;
    int tid = threadIdx.x;
    #pragma unroll
    for (int half = 0; half < 2; half++) {
        int d = half * 256 + tid;
        float acc = 0.f;
        for (int i = 0; i < 64; i++)
            acc += h[((size_t)(b_ * SEQ + t * 64 + i)) * DIM + d];
        partial[(size_t)bt * DIM + d] = acc;
    }
}

__global__ __launch_bounds__(256) void k_final(const float* __restrict__ partial,
        const float* __restrict__ Wout, float* __restrict__ out) {
    __shared__ float red[4][2];
    int tid = threadIdx.x;
    float acc0 = 0.f, acc1 = 0.f;
    #pragma unroll
    for (int half = 0; half < 2; half++) {
        int d = half * 256 + tid;
        float w = Wout[d];
        float s0 = 0.f, s1 = 0.f;
        for (int t = 0; t < 16; t++) {
            s0 += partial[t * DIM + d];
            s1 += partial[(16 + t) * DIM + d];
        }
        acc0 += s0 * w;
        acc1 += s1 * w;
    }
    #pragma unroll
    for (int off = 32; off > 0; off >>= 1) {
        acc0 += __shfl_down(acc0, off);
        acc1 += __shfl_down(acc1, off);
    }
    if ((tid & 63) == 0) { red[tid >> 6][0] = acc0; red[tid >> 6][1] = acc1; }
    __syncthreads();
    if (tid == 0) {
        out[0] = red[0][0] + red[1][0] + red[2][0] + red[3][0];
        out[1] = red[0][1] + red[1][1] + red[2][1] + red[3][1];
    }
}

extern "C" void kernel_launch(void* const* d_in, const int* in_sizes, int n_in,
                              void* d_out, int out_size, void* d_ws, size_t ws_size,
                              hipStream_t stream) {
    const float* x    = (const float*)d_in[0];
    const float* Wi   = (const float*)d_in[1];
    const float* bi   = (const float*)d_in[2];
    const float* Wq   = (const float*)d_in[3];
    const float* bq   = (const float*)d_in[4];
    const float* Wk   = (const float*)d_in[5];
    const float* bk   = (const float*)d_in[6];
    const float* Wv   = (const float*)d_in[7];
    const float* bv   = (const float*)d_in[8];
    const float* Er   = (const float*)d_in[9];
    const float* Wlin = (const float*)d_in[10];
    const float* blin = (const float*)d_in[11];
    const float* lng  = (const float*)d_in[12];
    const float* lnb  = (const float*)d_in[13];
    const float* Wout = (const float*)d_in[14];
    float* out = (float*)d_out;

    float* ws = (float*)d_ws;
    const size_t NBUF = (size_t)NB * SEQ * DIM;     // 1,048,576 floats
    float* h  = ws;
    float* q  = ws + NBUF;
    float* kk = ws + 2 * NBUF;
    float* vv = ws + 3 * NBUF;
    float* a  = ws + 4 * NBUF;
    float* y  = ws + 5 * NBUF;
    float* pa = ws + 6 * NBUF;                      // 32*512 partial sums

    k_init<<<dim3((NB * SEQ * DIM) / 256), dim3(256), 0, stream>>>(x, Wi, bi, h);
    for (int l = 0; l < NL; l++) {
        const size_t WO = (size_t)l * DIM * DIM;
        const size_t BO = (size_t)l * DIM;
        k_gemm_qkv<<<dim3(32, 24), dim3(256), 0, stream>>>(h, Wq + WO, bq + BO,
                Wk + WO, bk + BO, Wv + WO, bv + BO, q, kk, vv);
        k_attn<<<dim3(64, 16), dim3(256), 0, stream>>>(q, kk, vv,
                Er + (size_t)l * SEQ * DHD, a);
        k_gemm_one<<<dim3(32, 8), dim3(256), 0, stream>>>(a, Wlin + WO, blin + BO, y);
        k_ln_gelu_res<<<dim3(NB * SEQ), dim3(256), 0, stream>>>(y, lng + BO, lnb + BO, h);
    }
    k_colsum<<<dim3(32), dim3(256), 0, stream>>>(h, pa);
    k_final<<<dim3(1), dim3(256), 0, stream>>>(pa, Wout, out);
}

// Round 2
// 560.978 us; speedup vs baseline: 1.8470x; 1.8470x over previous
//
#include <hip/hip_runtime.h>
#include <math.h>

#define NL 4
#define DIM 512
#define NH 32
#define DHD 16
#define SEQ 1024
#define NB 2
#define LN_EPS 1e-5f
#define NEGF (-1e30f)

typedef _Float16 half4 __attribute__((ext_vector_type(4)));
typedef float floatx4 __attribute__((ext_vector_type(4)));

__device__ __forceinline__ float gelu_exact(float x) {
    return 0.5f * x * (1.0f + erff(x * 0.70710678118654752f));
}

// ---------------------------------------------------------------- init: h = gelu(x*Winit + binit)
__global__ __launch_bounds__(256) void k_init(const float* __restrict__ x,
        const float* __restrict__ Wi, const float* __restrict__ bi,
        float* __restrict__ h) {
    int idx = blockIdx.x * 256 + threadIdx.x;
    int d = idx & (DIM - 1);
    int bs = idx >> 9;                 // /DIM
    h[idx] = gelu_exact(x[bs] * Wi[d] + bi[d]);
}

// ---------------------------------------------------------------- fp32 tiled GEMM 64x64, BK=16
__device__ __forceinline__ void gemm_tile(const float* __restrict__ A,
        const float* __restrict__ W, const float* __restrict__ bias,
        float* __restrict__ C, int m0, int n0) {
    __shared__ float As[16][68];
    __shared__ float Bs[16][68];
    int tid = threadIdx.x;
    int tx = tid & 15, ty = tid >> 4;
    int arow = tid >> 2, acg = (tid & 3) << 2;
    int brow = tid >> 4, bcg = (tid & 15) << 2;
    float acc[4][4] = {{0.f}};
    for (int k0 = 0; k0 < DIM; k0 += 16) {
        float4 av = *(const float4*)(A + (size_t)(m0 + arow) * DIM + k0 + acg);
        float4 bv = *(const float4*)(W + (size_t)(k0 + brow) * DIM + n0 + bcg);
        As[acg + 0][arow] = av.x;
        As[acg + 1][arow] = av.y;
        As[acg + 2][arow] = av.z;
        As[acg + 3][arow] = av.w;
        *(float4*)&Bs[brow][bcg] = bv;
        __syncthreads();
        #pragma unroll
        for (int kk = 0; kk < 16; kk++) {
            float4 a4 = *(const float4*)&As[kk][ty << 2];
            float4 b4 = *(const float4*)&Bs[kk][tx << 2];
            float aa[4] = {a4.x, a4.y, a4.z, a4.w};
            float bb[4] = {b4.x, b4.y, b4.z, b4.w};
            #pragma unroll
            for (int i = 0; i < 4; i++)
                #pragma unroll
                for (int j = 0; j < 4; j++)
                    acc[i][j] = fmaf(aa[i], bb[j], acc[i][j]);
        }
        __syncthreads();
    }
    float bb4[4];
    #pragma unroll
    for (int j = 0; j < 4; j++) bb4[j] = bias[n0 + (tx << 2) + j];
    #pragma unroll
    for (int i = 0; i < 4; i++) {
        float4 r;
        r.x = acc[i][0] + bb4[0];
        r.y = acc[i][1] + bb4[1];
        r.z = acc[i][2] + bb4[2];
        r.w = acc[i][3] + bb4[3];
        *(float4*)(C + (size_t)(m0 + (ty << 2) + i) * DIM + n0 + (tx << 2)) = r;
    }
}

__global__ __launch_bounds__(256) void k_gemm_qkv(const float* __restrict__ h,
        const float* __restrict__ Wq, const float* __restrict__ bq,
        const float* __restrict__ Wk, const float* __restrict__ bk,
        const float* __restrict__ Wv, const float* __restrict__ bv,
        float* __restrict__ q, float* __restrict__ k, float* __restrict__ v) {
    int which = blockIdx.y >> 3;       // 0=q 1=k 2=v
    int nb = blockIdx.y & 7;
    const float* W = (which == 0) ? Wq : (which == 1) ? Wk : Wv;
    const float* bias = (which == 0) ? bq : (which == 1) ? bk : bv;
    float* C = (which == 0) ? q : (which == 1) ? k : v;
    gemm_tile(h, W, bias, C, blockIdx.x * 64, nb * 64);
}

__global__ __launch_bounds__(256) void k_gemm_one(const float* __restrict__ A,
        const float* __restrict__ W, const float* __restrict__ bias,
        float* __restrict__ C) {
    gemm_tile(A, W, bias, C, blockIdx.x * 64, blockIdx.y * 64);
}

// ---------------------------------------------------------------- MFMA causal rel-pos attention
// St = K·Q^T (transposed scores) so the St C-layout IS the B-frag layout for P·V:
// zero LDS transpose for P. Er term: QEr^T[j,s] via MFMA into skewed LDS buffer.
// Block = 256 thr (4 waves, 16 q-rows each). Grid (B*H, 8): block handles q-tile
// pair (64*y, 64*(15-y)) sequentially -> 17 chunk-iterations per block, uniform.
__global__ __launch_bounds__(256) void k_attn_mfma(const float* __restrict__ q,
        const float* __restrict__ k, const float* __restrict__ v,
        const float* __restrict__ Er, float* __restrict__ aout) {
    __shared__ _Float16 Ks[64][20];     // K chunk rows, pad 20 (10-bank stride)
    __shared__ _Float16 Vts[16][72];    // V^T: [d][t-local], stride 72 (8B aligned)
    __shared__ _Float16 Ers[128][20];   // Er ring, slot = j & 127
    __shared__ float Rel[4][80][18];    // per-wave skewed QEr^T, stride 18 (2-way max)
    const int tid = threadIdx.x;
    const int wid = tid >> 6;
    const int lane = tid & 63;
    const int nn = lane & 15;           // B-frag n-col / A-frag m-row
    const int a4 = (lane >> 4) << 2;    // k-group base
    const int b_ = blockIdx.x >> 5, h_ = blockIdx.x & 31;
    const float qscale = 0.25f * 1.44269504088896341f;  // 1/sqrt(DH) * log2(e)

    for (int ph = 0; ph < 2; ph++) {
        const int r0 = 64 * ((ph == 0) ? (int)blockIdx.y : (15 - (int)blockIdx.y));
        const int s0w = r0 + 16 * wid;
        // Q B-frag: lane holds Q[s0w + nn][a4 .. a4+3], pre-scaled
        const float* qp = q + ((size_t)(b_ * SEQ + s0w + nn)) * DIM + h_ * DHD + a4;
        float4 qv = *(const float4*)qp;
        half4 qf = { (_Float16)(qv.x * qscale), (_Float16)(qv.y * qscale),
                     (_Float16)(qv.z * qscale), (_Float16)(qv.w * qscale) };
        floatx4 O = {0.f, 0.f, 0.f, 0.f};
        float m = NEGF, lsum = 0.f;
        const int nchunks = (r0 >> 6) + 1;
        for (int ci = 0; ci < nchunks; ci++) {
            const int ct = ci << 6;
            __syncthreads();                       // protect LDS from prev iter readers
            {   // stage K + V (transposed) f16
                int t_ = tid & 63;
                int c4 = (tid >> 6) << 2;
                size_t gb = ((size_t)(b_ * SEQ + ct + t_)) * DIM + h_ * DHD + c4;
                float4 kv4 = *(const float4*)(k + gb);
                half4 kh = {(_Float16)kv4.x, (_Float16)kv4.y, (_Float16)kv4.z, (_Float16)kv4.w};
                *(half4*)&Ks[t_][c4] = kh;
                float4 vv4 = *(const float4*)(v + gb);
                Vts[c4 + 0][t_] = (_Float16)vv4.x;
                Vts[c4 + 1][t_] = (_Float16)vv4.y;
                Vts[c4 + 2][t_] = (_Float16)vv4.z;
                Vts[c4 + 3][t_] = (_Float16)vv4.w;
            }
            {   // stage Er ring: window [jb, jb+128); first chunk 128 rows, then 64 new
                int jb = SEQ - 64 - r0 + ct;
                int rounds = (ci == 0) ? 2 : 1;
                int rbase = (ci == 0) ? jb : jb + 64;
                for (int rr = 0; rr < rounds; rr++) {
                    int row = rbase + rr * 64 + (tid & 63);
                    int c4 = (tid >> 6) << 2;
                    int gr = (row < SEQ) ? row : (SEQ - 1);   // clamp: garbage rows are masked
                    float4 ev4 = *(const float4*)(Er + (size_t)gr * DHD + c4);
                    half4 eh = {(_Float16)ev4.x, (_Float16)ev4.y, (_Float16)ev4.z, (_Float16)ev4.w};
                    *(half4*)&Ers[row & 127][c4] = eh;
                }
            }
            __syncthreads();
            // --- QEr^T j-tiles -> skewed Rel (per-wave private)
            const int jbw = SEQ - 16 - s0w + ct;   // 16-aligned
            #pragma unroll
            for (int jt = 0; jt < 5; jt++) {
                int slot = (jbw + 16 * jt + nn) & 127;
                half4 ef = *(const half4*)&Ers[slot][a4];
                floatx4 acc = {0.f, 0.f, 0.f, 0.f};
                acc = __builtin_amdgcn_mfma_f32_16x16x16f16(ef, qf, acc, 0, 0, 0);
                #pragma unroll
                for (int r = 0; r < 4; r++)
                    Rel[wid][16 * jt + a4 + r][nn] = acc[r];
            }
            // --- St = K·Q^T tiles + Srel + causal mask
            float st[4][4];
            const bool diag = (ct == r0);
            #pragma unroll
            for (int tt = 0; tt < 4; tt++) {
                half4 kf = *(const half4*)&Ks[16 * tt + nn][a4];
                floatx4 acc = {0.f, 0.f, 0.f, 0.f};
                acc = __builtin_amdgcn_mfma_f32_16x16x16f16(kf, qf, acc, 0, 0, 0);
                #pragma unroll
                for (int r = 0; r < 4; r++) {
                    // Srel^T[t][s]: v = 15 - nn + t_local
                    float sv = acc[r] + Rel[wid][15 - nn + 16 * tt + a4 + r][nn];
                    if (diag && (16 * tt + a4 + r > 16 * wid + nn)) sv = NEGF;
                    st[tt][r] = sv;
                }
            }
            // --- online softmax over t (rows of St); state per s-col, exp2 domain
            float cmax = NEGF;
            #pragma unroll
            for (int tt = 0; tt < 4; tt++)
                #pragma unroll
                for (int r = 0; r < 4; r++) cmax = fmaxf(cmax, st[tt][r]);
            cmax = fmaxf(cmax, __shfl_xor(cmax, 16));
            cmax = fmaxf(cmax, __shfl_xor(cmax, 32));
            float mnew = fmaxf(m, cmax);
            float alpha = exp2f(m - mnew);         // m==NEGF -> 0, NaN-free
            m = mnew;
            float csum = 0.f;
            half4 pf[4];
            #pragma unroll
            for (int tt = 0; tt < 4; tt++) {
                float p0 = exp2f(st[tt][0] - m);
                float p1 = exp2f(st[tt][1] - m);
                float p2 = exp2f(st[tt][2] - m);
                float p3 = exp2f(st[tt][3] - m);
                csum += (p0 + p1) + (p2 + p3);
                half4 ph4 = {(_Float16)p0, (_Float16)p1, (_Float16)p2, (_Float16)p3};
                pf[tt] = ph4;
            }
            csum += __shfl_xor(csum, 16);
            csum += __shfl_xor(csum, 32);
            lsum = lsum * alpha + csum;
            O[0] *= alpha; O[1] *= alpha; O[2] *= alpha; O[3] *= alpha;
            // --- O^T += V^T · P  (pf IS the B-frag: no transpose)
            #pragma unroll
            for (int tt = 0; tt < 4; tt++) {
                half4 vf = *(const half4*)&Vts[nn][16 * tt + a4];
                O = __builtin_amdgcn_mfma_f32_16x16x16f16(vf, pf[tt], O, 0, 0, 0);
            }
        }
        float linv = 1.0f / lsum;
        float* op = aout + ((size_t)(b_ * SEQ + s0w + nn)) * DIM + h_ * DHD + a4;
        float4 ov = make_float4(O[0] * linv, O[1] * linv, O[2] * linv, O[3] * linv);
        *(float4*)op = ov;
    }
}

// ---------------------------------------------------------------- h += gelu(LN(y))
__global__ __launch_bounds__(256) void k_ln_gelu_res(const float* __restrict__ y,
        const float* __restrict__ gam, const float* __restrict__ bet,
        float* __restrict__ h) {
    __shared__ float red[8];
    int row = blockIdx.x, tid = threadIdx.x;
    const float* yr = y + (size_t)row * DIM;
    float v0 = yr[tid], v1 = yr[tid + 256];
    float sum = v0 + v1, sq = v0 * v0 + v1 * v1;
    #pragma unroll
    for (int off = 32; off > 0; off >>= 1) {
        sum += __shfl_down(sum, off);
        sq  += __shfl_down(sq, off);
    }
    if ((tid & 63) == 0) { red[tid >> 6] = sum; red[4 + (tid >> 6)] = sq; }
    __syncthreads();
    float ts = red[0] + red[1] + red[2] + red[3];
    float tq = red[4] + red[5] + red[6] + red[7];
    float mu = ts * (1.0f / DIM);
    float var = tq * (1.0f / DIM) - mu * mu;
    float rs = rsqrtf(var + LN_EPS);
    float z0 = (v0 - mu) * rs * gam[tid] + bet[tid];
    float z1 = (v1 - mu) * rs * gam[tid + 256] + bet[tid + 256];
    size_t base = (size_t)row * DIM;
    h[base + tid]       += gelu_exact(z0);
    h[base + tid + 256] += gelu_exact(z1);
}

// ---------------------------------------------------------------- final sum over S, dot with Wout
__global__ __launch_bounds__(256) void k_colsum(const float* __restrict__ h,
        float* __restrict__ partial) {
    int bt = blockIdx.x;               // b*16 + stile
    int b_ = bt >> 4, t = bt & 15;
    int tid = threadIdx.x;
    #pragma unroll
    for (int half = 0; half < 2; half++) {
        int d = half * 256 + tid;
        float acc = 0.f;
        for (int i = 0; i < 64; i++)
            acc += h[((size_t)(b_ * SEQ + t * 64 + i)) * DIM + d];
        partial[(size_t)bt * DIM + d] = acc;
    }
}

__global__ __launch_bounds__(256) void k_final(const float* __restrict__ partial,
        const float* __restrict__ Wout, float* __restrict__ out) {
    __shared__ float red[4][2];
    int tid = threadIdx.x;
    float acc0 = 0.f, acc1 = 0.f;
    #pragma unroll
    for (int half = 0; half < 2; half++) {
        int d = half * 256 + tid;
        float w = Wout[d];
        float s0 = 0.f, s1 = 0.f;
        for (int t = 0; t < 16; t++) {
            s0 += partial[t * DIM + d];
            s1 += partial[(16 + t) * DIM + d];
        }
        acc0 += s0 * w;
        acc1 += s1 * w;
    }
    #pragma unroll
    for (int off = 32; off > 0; off >>= 1) {
        acc0 += __shfl_down(acc0, off);
        acc1 += __shfl_down(acc1, off);
    }
    if ((tid & 63) == 0) { red[tid >> 6][0] = acc0; red[tid >> 6][1] = acc1; }
    __syncthreads();
    if (tid == 0) {
        out[0] = red[0][0] + red[1][0] + red[2][0] + red[3][0];
        out[1] = red[0][1] + red[1][1] + red[2][1] + red[3][1];
    }
}

extern "C" void kernel_launch(void* const* d_in, const int* in_sizes, int n_in,
                              void* d_out, int out_size, void* d_ws, size_t ws_size,
                              hipStream_t stream) {
    const float* x    = (const float*)d_in[0];
    const float* Wi   = (const float*)d_in[1];
    const float* bi   = (const float*)d_in[2];
    const float* Wq   = (const float*)d_in[3];
    const float* bq   = (const float*)d_in[4];
    const float* Wk   = (const float*)d_in[5];
    const float* bk   = (const float*)d_in[6];
    const float* Wv   = (const float*)d_in[7];
    const float* bv   = (const float*)d_in[8];
    const float* Er   = (const float*)d_in[9];
    const float* Wlin = (const float*)d_in[10];
    const float* blin = (const float*)d_in[11];
    const float* lng  = (const float*)d_in[12];
    const float* lnb  = (const float*)d_in[13];
    const float* Wout = (const float*)d_in[14];
    float* out = (float*)d_out;

    float* ws = (float*)d_ws;
    const size_t NBUF = (size_t)NB * SEQ * DIM;     // 1,048,576 floats
    float* h  = ws;
    float* q  = ws + NBUF;
    float* kk = ws + 2 * NBUF;
    float* vv = ws + 3 * NBUF;
    float* a  = ws + 4 * NBUF;
    float* y  = ws + 5 * NBUF;
    float* pa = ws + 6 * NBUF;                      // 32*512 partial sums

    k_init<<<dim3((NB * SEQ * DIM) / 256), dim3(256), 0, stream>>>(x, Wi, bi, h);
    for (int l = 0; l < NL; l++) {
        const size_t WO = (size_t)l * DIM * DIM;
        const size_t BO = (size_t)l * DIM;
        k_gemm_qkv<<<dim3(32, 24), dim3(256), 0, stream>>>(h, Wq + WO, bq + BO,
                Wk + WO, bk + BO, Wv + WO, bv + BO, q, kk, vv);
        k_attn_mfma<<<dim3(NB * NH, 8), dim3(256), 0, stream>>>(q, kk, vv,
                Er + (size_t)l * SEQ * DHD, a);
        k_gemm_one<<<dim3(32, 8), dim3(256), 0, stream>>>(a, Wlin + WO, blin + BO, y);
        k_ln_gelu_res<<<dim3(NB * SEQ), dim3(256), 0, stream>>>(y, lng + BO, lnb + BO, h);
    }
    k_colsum<<<dim3(32), dim3(256), 0, stream>>>(h, pa);
    k_final<<<dim3(1), dim3(256), 0, stream>>>(pa, Wout, out);
}

// Round 3
// 385.823 us; speedup vs baseline: 2.6856x; 1.4540x over previous
//
#include <hip/hip_runtime.h>
#include <math.h>

#define NL 4
#define DIM 512
#define NH 32
#define DHD 16
#define SEQ 1024
#define NB 2
#define LN_EPS 1e-5f
#define NEGF (-1e30f)
#define QSC 0.36067376022224085f   // 0.25 * log2(e), folded into Wq/bq

typedef _Float16 half4 __attribute__((ext_vector_type(4)));
typedef _Float16 half8 __attribute__((ext_vector_type(8)));
typedef float floatx4 __attribute__((ext_vector_type(4)));

__device__ __forceinline__ float gelu_exact(float x) {
    return 0.5f * x * (1.0f + erff(x * 0.70710678118654752f));
}

// ---------------------------------------------------------------- prep: W[k][n] -> Wt[n][k] f16
__global__ __launch_bounds__(256) void k_prep_w(const float* __restrict__ Wq,
        const float* __restrict__ Wk, const float* __restrict__ Wv,
        const float* __restrict__ Wlin, _Float16* __restrict__ Wqkvt,
        _Float16* __restrict__ Wlint) {
    __shared__ _Float16 lt[64][72];    // stride 72 f16 = 144B: rows 16B-aligned
    const int mz = blockIdx.z;
    const int l = mz >> 2, which = mz & 3;
    const float* src = (which == 0) ? Wq : (which == 1) ? Wk : (which == 2) ? Wv : Wlin;
    src += (size_t)l * 262144;
    const float scale = (which == 0) ? QSC : 1.0f;
    _Float16* dst = (which < 3) ? (Wqkvt + (size_t)l * 786432 + (size_t)which * 262144)
                                : (Wlint + (size_t)l * 262144);
    const int k0 = blockIdx.x << 6, n0 = blockIdx.y << 6;
    const int tid = threadIdx.x;
    #pragma unroll
    for (int p = 0; p < 4; p++) {
        int kl = (p << 4) + (tid >> 4);
        int n4 = (tid & 15) << 2;
        float4 wv = *(const float4*)(src + (size_t)(k0 + kl) * 512 + n0 + n4);
        lt[n4 + 0][kl] = (_Float16)(wv.x * scale);
        lt[n4 + 1][kl] = (_Float16)(wv.y * scale);
        lt[n4 + 2][kl] = (_Float16)(wv.z * scale);
        lt[n4 + 3][kl] = (_Float16)(wv.w * scale);
    }
    __syncthreads();
    int nl = tid >> 2, k16 = (tid & 3) << 4;
    float4* d4 = (float4*)(dst + (size_t)(n0 + nl) * 512 + k0 + k16);
    const float4* s4 = (const float4*)&lt[nl][k16];
    d4[0] = s4[0];
    d4[1] = s4[1];
}

// ---------------------------------------------------------------- prep: biases (bq scaled) + Er f16
__global__ __launch_bounds__(256) void k_prep_small(const float* __restrict__ bq,
        const float* __restrict__ bk, const float* __restrict__ bv,
        const float* __restrict__ Er, float* __restrict__ bqkv,
        _Float16* __restrict__ Erh) {
    int idx = blockIdx.x * 256 + threadIdx.x;
    if (idx < NL * 1536) {
        int l = idx / 1536, j = idx % 1536;
        int which = j >> 9, jj = j & 511;
        float val = (which == 0) ? bq[l * 512 + jj] * QSC
                  : (which == 1) ? bk[l * 512 + jj] : bv[l * 512 + jj];
        bqkv[idx] = val;
    }
    int e = idx - NL * 1536;
    if (e >= 0 && e < NL * SEQ * DHD) Erh[e] = (_Float16)Er[e];
}

// ---------------------------------------------------------------- init: h = gelu(x*Winit + binit)
__global__ __launch_bounds__(256) void k_init(const float* __restrict__ x,
        const float* __restrict__ Wi, const float* __restrict__ bi,
        float* __restrict__ h, _Float16* __restrict__ hf) {
    int idx = blockIdx.x * 256 + threadIdx.x;
    int d = idx & (DIM - 1);
    int bs = idx >> 9;
    float val = gelu_exact(x[bs] * Wi[d] + bi[d]);
    h[idx] = val;
    hf[idx] = (_Float16)val;
}

// ---------------------------------------------------------------- f16 MFMA GEMM, 128x128 tile BK=32
// A [2048][512] f16 row-major; Bt [Nt][512] f16 (pre-transposed weights).
// F16OUT=1: out = o16 + (colg>>9)*1M + rowg*512 + (colg&511)   (q|k|v contiguous)
// F16OUT=0: out = o32[rowg*512 + colg] (f32)
template<int F16OUT>
__global__ __launch_bounds__(256) void k_gemm_mfma(const _Float16* __restrict__ A,
        const _Float16* __restrict__ Bt, const float* __restrict__ bias,
        _Float16* __restrict__ o16, float* __restrict__ o32) {
    __shared__ _Float16 As[128][40];   // stride 40 f16 = 80B: 16B-aligned rows, <=2-way banks
    __shared__ _Float16 Bs[128][40];
    const int tid = threadIdx.x;
    const int w = tid >> 6, lane = tid & 63;
    const int wm = (w & 1) << 6, wn = (w >> 1) << 6;
    const int nn = lane & 15, qd = lane >> 4;
    const int m0 = blockIdx.x << 7, n0 = blockIdx.y << 7;
    floatx4 acc[4][4] = {};
    for (int k0 = 0; k0 < 512; k0 += 32) {
        __syncthreads();
        #pragma unroll
        for (int r = 0; r < 2; r++) {
            int c = tid + (r << 8);
            int row = c >> 2, kq = (c & 3) << 3;
            *(half8*)&As[row][kq] = *(const half8*)(A + (size_t)(m0 + row) * 512 + k0 + kq);
            *(half8*)&Bs[row][kq] = *(const half8*)(Bt + (size_t)(n0 + row) * 512 + k0 + kq);
        }
        __syncthreads();
        #pragma unroll
        for (int ks = 0; ks < 2; ks++) {
            half4 af[4], bf[4];
            #pragma unroll
            for (int t = 0; t < 4; t++) {
                af[t] = *(const half4*)&As[wm + (t << 4) + nn][(ks << 4) + (qd << 2)];
                bf[t] = *(const half4*)&Bs[wn + (t << 4) + nn][(ks << 4) + (qd << 2)];
            }
            #pragma unroll
            for (int ti = 0; ti < 4; ti++)
                #pragma unroll
                for (int tj = 0; tj < 4; tj++)
                    acc[ti][tj] = __builtin_amdgcn_mfma_f32_16x16x16f16(
                            af[ti], bf[tj], acc[ti][tj], 0, 0, 0);
        }
    }
    float bv[4];
    #pragma unroll
    for (int tj = 0; tj < 4; tj++) bv[tj] = bias[n0 + wn + (tj << 4) + nn];
    #pragma unroll
    for (int ti = 0; ti < 4; ti++) {
        int rowg = m0 + wm + (ti << 4) + (qd << 2);
        #pragma unroll
        for (int tj = 0; tj < 4; tj++) {
            int colg = n0 + wn + (tj << 4) + nn;
            #pragma unroll
            for (int r = 0; r < 4; r++) {
                float val = acc[ti][tj][r] + bv[tj];
                if (F16OUT) {
                    int which = colg >> 9, ci = colg & 511;
                    o16[(size_t)which * 1048576 + (size_t)(rowg + r) * 512 + ci] = (_Float16)val;
                } else {
                    o32[(size_t)(rowg + r) * 512 + colg] = val;
                }
            }
        }
    }
}

// ---------------------------------------------------------------- MFMA causal rel-pos attention (f16)
__global__ __launch_bounds__(256) void k_attn_mfma(const _Float16* __restrict__ q,
        const _Float16* __restrict__ k, const _Float16* __restrict__ v,
        const _Float16* __restrict__ Er, _Float16* __restrict__ aout) {
    __shared__ _Float16 Ks[64][20];
    __shared__ _Float16 Vts[16][72];
    __shared__ _Float16 Ers[128][20];
    __shared__ float Rel[4][16][84];   // [wave][s-col][j-local]: b128 writes, b32 reads
    const int tid = threadIdx.x;
    const int wid = tid >> 6;
    const int lane = tid & 63;
    const int nn = lane & 15;
    const int a4 = (lane >> 4) << 2;
    const int b_ = blockIdx.x >> 5, h_ = blockIdx.x & 31;
    const int t_ = tid >> 2, c4 = (tid & 3) << 2;

    for (int ph = 0; ph < 2; ph++) {
        const int r0 = 64 * ((ph == 0) ? (int)blockIdx.y : (15 - (int)blockIdx.y));
        const int s0w = r0 + 16 * wid;
        half4 qf = *(const half4*)(q + ((size_t)(b_ * SEQ + s0w + nn)) * DIM + h_ * DHD + a4);
        floatx4 O = {0.f, 0.f, 0.f, 0.f};
        float m = NEGF, lsum = 0.f;
        const int nchunks = (r0 >> 6) + 1;
        for (int ci = 0; ci < nchunks; ci++) {
            const int ct = ci << 6;
            __syncthreads();
            {   // stage K + V^T, coalesced 32B rows
                size_t gb = ((size_t)(b_ * SEQ + ct + t_)) * DIM + h_ * DHD + c4;
                *(half4*)&Ks[t_][c4] = *(const half4*)(k + gb);
                half4 vv4 = *(const half4*)(v + gb);
                Vts[c4 + 0][t_] = vv4.x;
                Vts[c4 + 1][t_] = vv4.y;
                Vts[c4 + 2][t_] = vv4.z;
                Vts[c4 + 3][t_] = vv4.w;
            }
            {   // stage Er ring [jb, jb+128)
                int jb = SEQ - 64 - r0 + ct;
                int rounds = (ci == 0) ? 2 : 1;
                int rbase = (ci == 0) ? jb : jb + 64;
                for (int rr = 0; rr < rounds; rr++) {
                    int row = rbase + rr * 64 + t_;
                    int gr = (row < SEQ) ? row : (SEQ - 1);   // masked rows: garbage OK
                    *(half4*)&Ers[row & 127][c4] = *(const half4*)(Er + (size_t)gr * DHD + c4);
                }
            }
            __syncthreads();
            // QEr^T j-tiles -> Rel[s][j] (b128 writes)
            const int jbw = SEQ - 16 - s0w + ct;
            #pragma unroll
            for (int jt = 0; jt < 5; jt++) {
                int slot = (jbw + 16 * jt + nn) & 127;
                half4 ef = *(const half4*)&Ers[slot][a4];
                floatx4 racc = {0.f, 0.f, 0.f, 0.f};
                racc = __builtin_amdgcn_mfma_f32_16x16x16f16(ef, qf, racc, 0, 0, 0);
                *(floatx4*)&Rel[wid][nn][16 * jt + a4] = racc;
            }
            // St = K·Q^T + Srel + causal mask
            float st[4][4];
            const bool diag = (ct == r0);
            #pragma unroll
            for (int tt = 0; tt < 4; tt++) {
                half4 kf = *(const half4*)&Ks[16 * tt + nn][a4];
                floatx4 sacc = {0.f, 0.f, 0.f, 0.f};
                sacc = __builtin_amdgcn_mfma_f32_16x16x16f16(kf, qf, sacc, 0, 0, 0);
                #pragma unroll
                for (int r = 0; r < 4; r++) {
                    int tl = 16 * tt + a4 + r;
                    float sv = sacc[r] + Rel[wid][nn][15 - nn + tl];
                    if (diag && (tl > 16 * wid + nn)) sv = NEGF;
                    st[tt][r] = sv;
                }
            }
            // online softmax (exp2 domain), state per s-col
            float cmax = NEGF;
            #pragma unroll
            for (int tt = 0; tt < 4; tt++)
                #pragma unroll
                for (int r = 0; r < 4; r++) cmax = fmaxf(cmax, st[tt][r]);
            cmax = fmaxf(cmax, __shfl_xor(cmax, 16));
            cmax = fmaxf(cmax, __shfl_xor(cmax, 32));
            float mnew = fmaxf(m, cmax);
            float alpha = exp2f(m - mnew);
            m = mnew;
            float csum = 0.f;
            half4 pf[4];
            #pragma unroll
            for (int tt = 0; tt < 4; tt++) {
                float p0 = exp2f(st[tt][0] - m);
                float p1 = exp2f(st[tt][1] - m);
                float p2 = exp2f(st[tt][2] - m);
                float p3 = exp2f(st[tt][3] - m);
                csum += (p0 + p1) + (p2 + p3);
                half4 ph4 = {(_Float16)p0, (_Float16)p1, (_Float16)p2, (_Float16)p3};
                pf[tt] = ph4;
            }
            csum += __shfl_xor(csum, 16);
            csum += __shfl_xor(csum, 32);
            lsum = lsum * alpha + csum;
            O[0] *= alpha; O[1] *= alpha; O[2] *= alpha; O[3] *= alpha;
            #pragma unroll
            for (int tt = 0; tt < 4; tt++) {
                half4 vf = *(const half4*)&Vts[nn][16 * tt + a4];
                O = __builtin_amdgcn_mfma_f32_16x16x16f16(vf, pf[tt], O, 0, 0, 0);
            }
        }
        float linv = 1.0f / lsum;
        half4 ov = { (_Float16)(O[0] * linv), (_Float16)(O[1] * linv),
                     (_Float16)(O[2] * linv), (_Float16)(O[3] * linv) };
        *(half4*)(aout + ((size_t)(b_ * SEQ + s0w + nn)) * DIM + h_ * DHD + a4) = ov;
    }
}

// ---------------------------------------------------------------- h += gelu(LN(y)); also h f16 copy
__global__ __launch_bounds__(256) void k_ln_gelu_res(const float* __restrict__ y,
        const float* __restrict__ gam, const float* __restrict__ bet,
        float* __restrict__ h, _Float16* __restrict__ hf) {
    __shared__ float red[8];
    int row = blockIdx.x, tid = threadIdx.x;
    const float* yr = y + (size_t)row * DIM;
    float v0 = yr[tid], v1 = yr[tid + 256];
    float sum = v0 + v1, sq = v0 * v0 + v1 * v1;
    #pragma unroll
    for (int off = 32; off > 0; off >>= 1) {
        sum += __shfl_down(sum, off);
        sq  += __shfl_down(sq, off);
    }
    if ((tid & 63) == 0) { red[tid >> 6] = sum; red[4 + (tid >> 6)] = sq; }
    __syncthreads();
    float ts = red[0] + red[1] + red[2] + red[3];
    float tq = red[4] + red[5] + red[6] + red[7];
    float mu = ts * (1.0f / DIM);
    float var = tq * (1.0f / DIM) - mu * mu;
    float rs = rsqrtf(var + LN_EPS);
    float z0 = (v0 - mu) * rs * gam[tid] + bet[tid];
    float z1 = (v1 - mu) * rs * gam[tid + 256] + bet[tid + 256];
    size_t base = (size_t)row * DIM;
    float nh0 = h[base + tid] + gelu_exact(z0);
    float nh1 = h[base + tid + 256] + gelu_exact(z1);
    h[base + tid] = nh0;
    h[base + tid + 256] = nh1;
    hf[base + tid] = (_Float16)nh0;
    hf[base + tid + 256] = (_Float16)nh1;
}

// ---------------------------------------------------------------- final sum over S, dot with Wout
__global__ __launch_bounds__(256) void k_colsum(const float* __restrict__ h,
        float* __restrict__ partial) {
    int bt = blockIdx.x;
    int b_ = bt >> 4, t = bt & 15;
    int tid = threadIdx.x;
    #pragma unroll
    for (int half = 0; half < 2; half++) {
        int d = half * 256 + tid;
        float acc = 0.f;
        for (int i = 0; i < 64; i++)
            acc += h[((size_t)(b_ * SEQ + t * 64 + i)) * DIM + d];
        partial[(size_t)bt * DIM + d] = acc;
    }
}

__global__ __launch_bounds__(256) void k_final(const float* __restrict__ partial,
        const float* __restrict__ Wout, float* __restrict__ out) {
    __shared__ float red[4][2];
    int tid = threadIdx.x;
    float acc0 = 0.f, acc1 = 0.f;
    #pragma unroll
    for (int half = 0; half < 2; half++) {
        int d = half * 256 + tid;
        float w = Wout[d];
        float s0 = 0.f, s1 = 0.f;
        for (int t = 0; t < 16; t++) {
            s0 += partial[t * DIM + d];
            s1 += partial[(16 + t) * DIM + d];
        }
        acc0 += s0 * w;
        acc1 += s1 * w;
    }
    #pragma unroll
    for (int off = 32; off > 0; off >>= 1) {
        acc0 += __shfl_down(acc0, off);
        acc1 += __shfl_down(acc1, off);
    }
    if ((tid & 63) == 0) { red[tid >> 6][0] = acc0; red[tid >> 6][1] = acc1; }
    __syncthreads();
    if (tid == 0) {
        out[0] = red[0][0] + red[1][0] + red[2][0] + red[3][0];
        out[1] = red[0][1] + red[1][1] + red[2][1] + red[3][1];
    }
}

extern "C" void kernel_launch(void* const* d_in, const int* in_sizes, int n_in,
                              void* d_out, int out_size, void* d_ws, size_t ws_size,
                              hipStream_t stream) {
    const float* x    = (const float*)d_in[0];
    const float* Wi   = (const float*)d_in[1];
    const float* bi   = (const float*)d_in[2];
    const float* Wq   = (const float*)d_in[3];
    const float* bq   = (const float*)d_in[4];
    const float* Wk   = (const float*)d_in[5];
    const float* bk   = (const float*)d_in[6];
    const float* Wv   = (const float*)d_in[7];
    const float* bv   = (const float*)d_in[8];
    const float* Er   = (const float*)d_in[9];
    const float* Wlin = (const float*)d_in[10];
    const float* blin = (const float*)d_in[11];
    const float* lng  = (const float*)d_in[12];
    const float* lnb  = (const float*)d_in[13];
    const float* Wout = (const float*)d_in[14];
    float* out = (float*)d_out;

    float* ws = (float*)d_ws;
    const size_t N1 = 1048576;                       // B*S*D
    float*     h     = ws;                           // [0, 1.0N)
    _Float16*  hf    = (_Float16*)(ws + N1);         // [1.0N, 1.5N)
    _Float16*  qh    = (_Float16*)(ws + N1 + N1/2);  // [1.5N, 2.0N)  (k,v follow contiguously)
    float*     y     = ws + N1 + N1/2;               // aliases q/k (dead by then)
    _Float16*  ah    = (_Float16*)(ws + 3 * N1);     // [3.0N, 3.5N)
    _Float16*  Wqkvt = (_Float16*)(ws + 3 * N1 + N1/2);  // [3.5N, 5.0N)
    _Float16*  Wlint = (_Float16*)(ws + 5 * N1);         // [5.0N, 5.5N)
    float*     bqkv  = ws + 5 * N1 + N1/2;
    _Float16*  Erh   = (_Float16*)(ws + 5 * N1 + N1/2 + 8192);
    float*     pa    = ws + 5 * N1 + N1/2 + 8192 + 32768;

    k_prep_w<<<dim3(8, 8, 16), dim3(256), 0, stream>>>(Wq, Wk, Wv, Wlin, Wqkvt, Wlint);
    k_prep_small<<<dim3(280), dim3(256), 0, stream>>>(bq, bk, bv, Er, bqkv, Erh);
    k_init<<<dim3(4096), dim3(256), 0, stream>>>(x, Wi, bi, h, hf);
    for (int l = 0; l < NL; l++) {
        k_gemm_mfma<1><<<dim3(16, 12), dim3(256), 0, stream>>>(
                hf, Wqkvt + (size_t)l * 786432, bqkv + l * 1536, qh, nullptr);
        k_attn_mfma<<<dim3(NB * NH, 8), dim3(256), 0, stream>>>(
                qh, qh + 1048576, qh + 2097152, Erh + (size_t)l * 16384, ah);
        k_gemm_mfma<0><<<dim3(16, 4), dim3(256), 0, stream>>>(
                ah, Wlint + (size_t)l * 262144, blin + l * 512, nullptr, y);
        k_ln_gelu_res<<<dim3(NB * SEQ), dim3(256), 0, stream>>>(
                y, lng + l * 512, lnb + l * 512, h, hf);
    }
    k_colsum<<<dim3(32), dim3(256), 0, stream>>>(h, pa);
    k_final<<<dim3(1), dim3(256), 0, stream>>>(pa, Wout, out);
}

// Round 4
// 327.424 us; speedup vs baseline: 3.1645x; 1.1784x over previous
//
#include <hip/hip_runtime.h>
#include <math.h>

#define NL 4
#define DIM 512
#define NH 32
#define DHD 16
#define SEQ 1024
#define NB 2
#define LN_EPS 1e-5f
#define NEGF (-1e30f)
#define QSC 0.36067376022224085f   // 0.25 * log2(e), folded into Wq/bq

typedef _Float16 half4 __attribute__((ext_vector_type(4)));
typedef _Float16 half8 __attribute__((ext_vector_type(8)));
typedef float floatx4 __attribute__((ext_vector_type(4)));

__device__ __forceinline__ float gelu_exact(float x) {
    return 0.5f * x * (1.0f + erff(x * 0.70710678118654752f));
}

// ---------------------------------------------------------------- prep: W[k][n] -> Wt[n][k] f16
__global__ __launch_bounds__(256) void k_prep_w(const float* __restrict__ Wq,
        const float* __restrict__ Wk, const float* __restrict__ Wv,
        const float* __restrict__ Wlin, _Float16* __restrict__ Wqkvt,
        _Float16* __restrict__ Wlint) {
    __shared__ _Float16 lt[64][72];
    const int mz = blockIdx.z;
    const int l = mz >> 2, which = mz & 3;
    const float* src = (which == 0) ? Wq : (which == 1) ? Wk : (which == 2) ? Wv : Wlin;
    src += (size_t)l * 262144;
    const float scale = (which == 0) ? QSC : 1.0f;
    _Float16* dst = (which < 3) ? (Wqkvt + (size_t)l * 786432 + (size_t)which * 262144)
                                : (Wlint + (size_t)l * 262144);
    const int k0 = blockIdx.x << 6, n0 = blockIdx.y << 6;
    const int tid = threadIdx.x;
    #pragma unroll
    for (int p = 0; p < 4; p++) {
        int kl = (p << 4) + (tid >> 4);
        int n4 = (tid & 15) << 2;
        float4 wv = *(const float4*)(src + (size_t)(k0 + kl) * 512 + n0 + n4);
        lt[n4 + 0][kl] = (_Float16)(wv.x * scale);
        lt[n4 + 1][kl] = (_Float16)(wv.y * scale);
        lt[n4 + 2][kl] = (_Float16)(wv.z * scale);
        lt[n4 + 3][kl] = (_Float16)(wv.w * scale);
    }
    __syncthreads();
    int nl = tid >> 2, k16 = (tid & 3) << 4;
    float4* d4 = (float4*)(dst + (size_t)(n0 + nl) * 512 + k0 + k16);
    const float4* s4 = (const float4*)&lt[nl][k16];
    d4[0] = s4[0];
    d4[1] = s4[1];
}

// ---------------------------------------------------------------- prep: biases (bq scaled) + Er f16
__global__ __launch_bounds__(256) void k_prep_small(const float* __restrict__ bq,
        const float* __restrict__ bk, const float* __restrict__ bv,
        const float* __restrict__ Er, float* __restrict__ bqkv,
        _Float16* __restrict__ Erh) {
    int idx = blockIdx.x * 256 + threadIdx.x;
    if (idx < NL * 1536) {
        int l = idx / 1536, j = idx % 1536;
        int which = j >> 9, jj = j & 511;
        float val = (which == 0) ? bq[l * 512 + jj] * QSC
                  : (which == 1) ? bk[l * 512 + jj] : bv[l * 512 + jj];
        bqkv[idx] = val;
    }
    int e = idx - NL * 1536;
    if (e >= 0 && e < NL * SEQ * DHD) Erh[e] = (_Float16)Er[e];
}

// ---------------------------------------------------------------- init: h = gelu(x*Winit + binit)
__global__ __launch_bounds__(256) void k_init(const float* __restrict__ x,
        const float* __restrict__ Wi, const float* __restrict__ bi,
        float* __restrict__ h, _Float16* __restrict__ hf) {
    int idx = blockIdx.x * 256 + threadIdx.x;
    int d = idx & (DIM - 1);
    int bs = idx >> 9;
    float val = gelu_exact(x[bs] * Wi[d] + bi[d]);
    h[idx] = val;
    hf[idx] = (_Float16)val;
}

// ---------------------------------------------------------------- f16 MFMA GEMM, 64x128 tile, BK=64, x32
// A [2048][512] f16 row-major; Bt [Nt][512] f16 (pre-transposed).
// wave tile 32x64: acc[2][4]. A-frag (x32): A[m=lane&15][k=quad*8+j].
template<int F16OUT>
__global__ __launch_bounds__(256) void k_gemm_mfma(const _Float16* __restrict__ A,
        const _Float16* __restrict__ Bt, const float* __restrict__ bias,
        _Float16* __restrict__ o16, float* __restrict__ o32) {
    __shared__ _Float16 As[64][72];    // stride 72 f16 = 144 B: 16B-aligned rows
    __shared__ _Float16 Bs[128][72];
    const int tid = threadIdx.x;
    const int w = tid >> 6, lane = tid & 63;
    const int wm = (w & 1) << 5;       // 0 / 32
    const int wn = (w >> 1) << 6;      // 0 / 64
    const int nn = lane & 15, qd = lane >> 4;
    const int m0 = blockIdx.x << 6, n0 = blockIdx.y << 7;
    floatx4 acc[2][4] = {};
    for (int k0 = 0; k0 < 512; k0 += 64) {
        __syncthreads();
        #pragma unroll
        for (int r = 0; r < 2; r++) {                   // A: 64x64 = 512 half8 chunks
            int c = tid + (r << 8);
            int row = c >> 3, k8 = (c & 7) << 3;
            *(half8*)&As[row][k8] = *(const half8*)(A + (size_t)(m0 + row) * 512 + k0 + k8);
        }
        #pragma unroll
        for (int r = 0; r < 4; r++) {                   // B: 128x64 = 1024 chunks
            int c = tid + (r << 8);
            int row = c >> 3, k8 = (c & 7) << 3;
            *(half8*)&Bs[row][k8] = *(const half8*)(Bt + (size_t)(n0 + row) * 512 + k0 + k8);
        }
        __syncthreads();
        #pragma unroll
        for (int ks = 0; ks < 2; ks++) {
            half8 af[2], bf[4];
            #pragma unroll
            for (int t = 0; t < 2; t++)
                af[t] = *(const half8*)&As[wm + (t << 4) + nn][(ks << 5) + (qd << 3)];
            #pragma unroll
            for (int t = 0; t < 4; t++)
                bf[t] = *(const half8*)&Bs[wn + (t << 4) + nn][(ks << 5) + (qd << 3)];
            #pragma unroll
            for (int ti = 0; ti < 2; ti++)
                #pragma unroll
                for (int tj = 0; tj < 4; tj++)
                    acc[ti][tj] = __builtin_amdgcn_mfma_f32_16x16x32_f16(
                            af[ti], bf[tj], acc[ti][tj], 0, 0, 0);
        }
    }
    float bv[4];
    #pragma unroll
    for (int tj = 0; tj < 4; tj++) bv[tj] = bias[n0 + wn + (tj << 4) + nn];
    #pragma unroll
    for (int ti = 0; ti < 2; ti++) {
        int rowg = m0 + wm + (ti << 4) + (qd << 2);
        #pragma unroll
        for (int tj = 0; tj < 4; tj++) {
            int colg = n0 + wn + (tj << 4) + nn;
            #pragma unroll
            for (int r = 0; r < 4; r++) {
                float val = acc[ti][tj][r] + bv[tj];
                if (F16OUT) {
                    int which = colg >> 9, ci = colg & 511;
                    o16[(size_t)which * 1048576 + (size_t)(rowg + r) * 512 + ci] = (_Float16)val;
                } else {
                    o32[(size_t)(rowg + r) * 512 + colg] = val;
                }
            }
        }
    }
}

// ---------------------------------------------------------------- MFMA causal rel-pos attention (f16)
// Block = (b,h, y): phases r0 = {64y, 64(15-y)} share K/V staged per 512-row part.
// 4 barriers/block total; Er read direct from global (L1-resident).
__global__ __launch_bounds__(256) void k_attn_mfma(const _Float16* __restrict__ q,
        const _Float16* __restrict__ k, const _Float16* __restrict__ v,
        const _Float16* __restrict__ Er, _Float16* __restrict__ aout) {
    __shared__ _Float16 Ks[512][20];    // stride 20: conflict-free b64 frag reads
    __shared__ _Float16 Vts[16][520];   // V^T, stride 520: 2-way max
    __shared__ float Rel[4][16][84];    // per-wave skewed QEr^T
    const int tid = threadIdx.x;
    const int wid = tid >> 6, lane = tid & 63;
    const int nn = lane & 15, a4 = (lane >> 4) << 2;
    const int b_ = blockIdx.x >> 5, h_ = blockIdx.x & 31;
    const int y = blockIdx.y;
    const int t_ = tid >> 2, c4 = (tid & 3) << 2;
    const int r0p[2] = {64 * y, 64 * (15 - y)};        // r0p[1] >= r0p[0]
    const int R = r0p[1] + 64;

    half4 qf[2];
    floatx4 O[2];
    float m[2], lsum[2];
    #pragma unroll
    for (int ph = 0; ph < 2; ph++) {
        int s0w = r0p[ph] + 16 * wid;
        qf[ph] = *(const half4*)(q + ((size_t)(b_ * SEQ + s0w + nn)) * DIM + h_ * DHD + a4);
        O[ph] = (floatx4){0.f, 0.f, 0.f, 0.f};
        m[ph] = NEGF;
        lsum[ph] = 0.f;
    }

    for (int part = 0; part < 2; part++) {
        const int p0 = part << 9;
        if (p0 >= R) break;
        const int pend = (R < p0 + 512) ? R : (p0 + 512);
        __syncthreads();
        const int ng = (pend - p0) >> 6;
        for (int g = 0; g < ng; g++) {                 // stage K + V^T rows [p0, pend)
            int rl = (g << 6) + t_;
            size_t gb = ((size_t)(b_ * SEQ + p0 + rl)) * DIM + h_ * DHD + c4;
            *(half4*)&Ks[rl][c4] = *(const half4*)(k + gb);
            half4 vv4 = *(const half4*)(v + gb);
            Vts[c4 + 0][rl] = vv4.x;
            Vts[c4 + 1][rl] = vv4.y;
            Vts[c4 + 2][rl] = vv4.z;
            Vts[c4 + 3][rl] = vv4.w;
        }
        __syncthreads();
        #pragma unroll
        for (int ph = 0; ph < 2; ph++) {
            const int r0 = r0p[ph];
            const int s0w = r0 + 16 * wid;
            const int hi = (r0 + 64 < pend) ? (r0 + 64) : pend;
            for (int ct = p0; ct < hi; ct += 64) {
                const int ctl = ct - p0;
                // QEr^T j-tiles -> Rel (Er direct from global; clamped rows are masked later)
                const int jbw = 1008 - s0w + ct;
                #pragma unroll
                for (int jt = 0; jt < 5; jt++) {
                    int j = jbw + (jt << 4) + nn;
                    j = (j < SEQ - 1) ? j : (SEQ - 1);
                    half4 ef = *(const half4*)(Er + (size_t)j * DHD + a4);
                    floatx4 racc = {0.f, 0.f, 0.f, 0.f};
                    racc = __builtin_amdgcn_mfma_f32_16x16x16f16(ef, qf[ph], racc, 0, 0, 0);
                    *(floatx4*)&Rel[wid][nn][(jt << 4) + a4] = racc;
                }
                // St = K·Q^T + Srel + causal mask
                float st[4][4];
                const bool diag = (ct == r0);
                #pragma unroll
                for (int tt = 0; tt < 4; tt++) {
                    half4 kf = *(const half4*)&Ks[ctl + (tt << 4) + nn][a4];
                    floatx4 sacc = {0.f, 0.f, 0.f, 0.f};
                    sacc = __builtin_amdgcn_mfma_f32_16x16x16f16(kf, qf[ph], sacc, 0, 0, 0);
                    #pragma unroll
                    for (int r = 0; r < 4; r++) {
                        int tl = (tt << 4) + a4 + r;
                        float sv = sacc[r] + Rel[wid][nn][15 - nn + tl];
                        if (diag && (tl > 16 * wid + nn)) sv = NEGF;
                        st[tt][r] = sv;
                    }
                }
                // online softmax (exp2 domain), state per s-col
                float cmax = NEGF;
                #pragma unroll
                for (int tt = 0; tt < 4; tt++)
                    #pragma unroll
                    for (int r = 0; r < 4; r++) cmax = fmaxf(cmax, st[tt][r]);
                cmax = fmaxf(cmax, __shfl_xor(cmax, 16));
                cmax = fmaxf(cmax, __shfl_xor(cmax, 32));
                float mnew = fmaxf(m[ph], cmax);
                float alpha = exp2f(m[ph] - mnew);
                m[ph] = mnew;
                float csum = 0.f;
                half4 pf[4];
                #pragma unroll
                for (int tt = 0; tt < 4; tt++) {
                    float p0e = exp2f(st[tt][0] - mnew);
                    float p1e = exp2f(st[tt][1] - mnew);
                    float p2e = exp2f(st[tt][2] - mnew);
                    float p3e = exp2f(st[tt][3] - mnew);
                    csum += (p0e + p1e) + (p2e + p3e);
                    half4 ph4 = {(_Float16)p0e, (_Float16)p1e, (_Float16)p2e, (_Float16)p3e};
                    pf[tt] = ph4;
                }
                csum += __shfl_xor(csum, 16);
                csum += __shfl_xor(csum, 32);
                lsum[ph] = lsum[ph] * alpha + csum;
                O[ph][0] *= alpha; O[ph][1] *= alpha; O[ph][2] *= alpha; O[ph][3] *= alpha;
                #pragma unroll
                for (int tt = 0; tt < 4; tt++) {
                    half4 vf = *(const half4*)&Vts[nn][ctl + (tt << 4) + a4];
                    O[ph] = __builtin_amdgcn_mfma_f32_16x16x16f16(vf, pf[tt], O[ph], 0, 0, 0);
                }
            }
        }
    }
    #pragma unroll
    for (int ph = 0; ph < 2; ph++) {
        float linv = 1.0f / lsum[ph];
        int s0w = r0p[ph] + 16 * wid;
        half4 ov = { (_Float16)(O[ph][0] * linv), (_Float16)(O[ph][1] * linv),
                     (_Float16)(O[ph][2] * linv), (_Float16)(O[ph][3] * linv) };
        *(half4*)(aout + ((size_t)(b_ * SEQ + s0w + nn)) * DIM + h_ * DHD + a4) = ov;
    }
}

// ---------------------------------------------------------------- h += gelu(LN(y)); also h f16 copy
__global__ __launch_bounds__(256) void k_ln_gelu_res(const float* __restrict__ y,
        const float* __restrict__ gam, const float* __restrict__ bet,
        float* __restrict__ h, _Float16* __restrict__ hf) {
    __shared__ float red[8];
    int row = blockIdx.x, tid = threadIdx.x;
    const float* yr = y + (size_t)row * DIM;
    float v0 = yr[tid], v1 = yr[tid + 256];
    float sum = v0 + v1, sq = v0 * v0 + v1 * v1;
    #pragma unroll
    for (int off = 32; off > 0; off >>= 1) {
        sum += __shfl_down(sum, off);
        sq  += __shfl_down(sq, off);
    }
    if ((tid & 63) == 0) { red[tid >> 6] = sum; red[4 + (tid >> 6)] = sq; }
    __syncthreads();
    float ts = red[0] + red[1] + red[2] + red[3];
    float tq = red[4] + red[5] + red[6] + red[7];
    float mu = ts * (1.0f / DIM);
    float var = tq * (1.0f / DIM) - mu * mu;
    float rs = rsqrtf(var + LN_EPS);
    float z0 = (v0 - mu) * rs * gam[tid] + bet[tid];
    float z1 = (v1 - mu) * rs * gam[tid + 256] + bet[tid + 256];
    size_t base = (size_t)row * DIM;
    float nh0 = h[base + tid] + gelu_exact(z0);
    float nh1 = h[base + tid + 256] + gelu_exact(z1);
    h[base + tid] = nh0;
    h[base + tid + 256] = nh1;
    hf[base + tid] = (_Float16)nh0;
    hf[base + tid + 256] = (_Float16)nh1;
}

// ---------------------------------------------------------------- final sum over S, dot with Wout
__global__ __launch_bounds__(256) void k_colsum(const float* __restrict__ h,
        float* __restrict__ partial) {
    int bt = blockIdx.x;
    int b_ = bt >> 4, t = bt & 15;
    int tid = threadIdx.x;
    #pragma unroll
    for (int half = 0; half < 2; half++) {
        int d = half * 256 + tid;
        float acc = 0.f;
        for (int i = 0; i < 64; i++)
            acc += h[((size_t)(b_ * SEQ + t * 64 + i)) * DIM + d];
        partial[(size_t)bt * DIM + d] = acc;
    }
}

__global__ __launch_bounds__(256) void k_final(const float* __restrict__ partial,
        const float* __restrict__ Wout, float* __restrict__ out) {
    __shared__ float red[4][2];
    int tid = threadIdx.x;
    float acc0 = 0.f, acc1 = 0.f;
    #pragma unroll
    for (int half = 0; half < 2; half++) {
        int d = half * 256 + tid;
        float w = Wout[d];
        float s0 = 0.f, s1 = 0.f;
        for (int t = 0; t < 16; t++) {
            s0 += partial[t * DIM + d];
            s1 += partial[(16 + t) * DIM + d];
        }
        acc0 += s0 * w;
        acc1 += s1 * w;
    }
    #pragma unroll
    for (int off = 32; off > 0; off >>= 1) {
        acc0 += __shfl_down(acc0, off);
        acc1 += __shfl_down(acc1, off);
    }
    if ((tid & 63) == 0) { red[tid >> 6][0] = acc0; red[tid >> 6][1] = acc1; }
    __syncthreads();
    if (tid == 0) {
        out[0] = red[0][0] + red[1][0] + red[2][0] + red[3][0];
        out[1] = red[0][1] + red[1][1] + red[2][1] + red[3][1];
    }
}

extern "C" void kernel_launch(void* const* d_in, const int* in_sizes, int n_in,
                              void* d_out, int out_size, void* d_ws, size_t ws_size,
                              hipStream_t stream) {
    const float* x    = (const float*)d_in[0];
    const float* Wi   = (const float*)d_in[1];
    const float* bi   = (const float*)d_in[2];
    const float* Wq   = (const float*)d_in[3];
    const float* bq   = (const float*)d_in[4];
    const float* Wk   = (const float*)d_in[5];
    const float* bk   = (const float*)d_in[6];
    const float* Wv   = (const float*)d_in[7];
    const float* bv   = (const float*)d_in[8];
    const float* Er   = (const float*)d_in[9];
    const float* Wlin = (const float*)d_in[10];
    const float* blin = (const float*)d_in[11];
    const float* lng  = (const float*)d_in[12];
    const float* lnb  = (const float*)d_in[13];
    const float* Wout = (const float*)d_in[14];
    float* out = (float*)d_out;

    float* ws = (float*)d_ws;
    const size_t N1 = 1048576;                       // B*S*D
    float*     h     = ws;
    _Float16*  hf    = (_Float16*)(ws + N1);
    _Float16*  qh    = (_Float16*)(ws + N1 + N1/2);  // q,k,v contiguous f16
    float*     y     = ws + N1 + N1/2;               // aliases q/k (dead by then)
    _Float16*  ah    = (_Float16*)(ws + 3 * N1);
    _Float16*  Wqkvt = (_Float16*)(ws + 3 * N1 + N1/2);
    _Float16*  Wlint = (_Float16*)(ws + 5 * N1);
    float*     bqkv  = ws + 5 * N1 + N1/2;
    _Float16*  Erh   = (_Float16*)(ws + 5 * N1 + N1/2 + 8192);
    float*     pa    = ws + 5 * N1 + N1/2 + 8192 + 32768;

    k_prep_w<<<dim3(8, 8, 16), dim3(256), 0, stream>>>(Wq, Wk, Wv, Wlin, Wqkvt, Wlint);
    k_prep_small<<<dim3(280), dim3(256), 0, stream>>>(bq, bk, bv, Er, bqkv, Erh);
    k_init<<<dim3(4096), dim3(256), 0, stream>>>(x, Wi, bi, h, hf);
    for (int l = 0; l < NL; l++) {
        k_gemm_mfma<1><<<dim3(32, 12), dim3(256), 0, stream>>>(
                hf, Wqkvt + (size_t)l * 786432, bqkv + l * 1536, qh, nullptr);
        k_attn_mfma<<<dim3(NB * NH, 8), dim3(256), 0, stream>>>(
                qh, qh + 1048576, qh + 2097152, Erh + (size_t)l * 16384, ah);
        k_gemm_mfma<0><<<dim3(32, 4), dim3(256), 0, stream>>>(
                ah, Wlint + (size_t)l * 262144, blin + l * 512, nullptr, y);
        k_ln_gelu_res<<<dim3(NB * SEQ), dim3(256), 0, stream>>>(
                y, lng + l * 512, lnb + l * 512, h, hf);
    }
    k_colsum<<<dim3(32), dim3(256), 0, stream>>>(h, pa);
    k_final<<<dim3(1), dim3(256), 0, stream>>>(pa, Wout, out);
}

// Round 5
// 322.260 us; speedup vs baseline: 3.2153x; 1.0160x over previous
//
#include <hip/hip_runtime.h>
#include <math.h>

#define NL 4
#define DIM 512
#define NH 32
#define DHD 16
#define SEQ 1024
#define NB 2
#define LN_EPS 1e-5f
#define NEGF (-1e30f)
#define QSC 0.36067376022224085f   // 0.25 * log2(e), folded into Wq/bq

typedef _Float16 half4 __attribute__((ext_vector_type(4)));
typedef _Float16 half8 __attribute__((ext_vector_type(8)));
typedef float floatx4 __attribute__((ext_vector_type(4)));

__device__ __forceinline__ float gelu_exact(float x) {
    return 0.5f * x * (1.0f + erff(x * 0.70710678118654752f));
}

// ---------------------------------------------------------------- prep: W[k][n] -> Wt[n][k] f16
__global__ __launch_bounds__(256) void k_prep_w(const float* __restrict__ Wq,
        const float* __restrict__ Wk, const float* __restrict__ Wv,
        const float* __restrict__ Wlin, _Float16* __restrict__ Wqkvt,
        _Float16* __restrict__ Wlint) {
    __shared__ _Float16 lt[64][72];
    const int mz = blockIdx.z;
    const int l = mz >> 2, which = mz & 3;
    const float* src = (which == 0) ? Wq : (which == 1) ? Wk : (which == 2) ? Wv : Wlin;
    src += (size_t)l * 262144;
    const float scale = (which == 0) ? QSC : 1.0f;
    _Float16* dst = (which < 3) ? (Wqkvt + (size_t)l * 786432 + (size_t)which * 262144)
                                : (Wlint + (size_t)l * 262144);
    const int k0 = blockIdx.x << 6, n0 = blockIdx.y << 6;
    const int tid = threadIdx.x;
    #pragma unroll
    for (int p = 0; p < 4; p++) {
        int kl = (p << 4) + (tid >> 4);
        int n4 = (tid & 15) << 2;
        float4 wv = *(const float4*)(src + (size_t)(k0 + kl) * 512 + n0 + n4);
        lt[n4 + 0][kl] = (_Float16)(wv.x * scale);
        lt[n4 + 1][kl] = (_Float16)(wv.y * scale);
        lt[n4 + 2][kl] = (_Float16)(wv.z * scale);
        lt[n4 + 3][kl] = (_Float16)(wv.w * scale);
    }
    __syncthreads();
    int nl = tid >> 2, k16 = (tid & 3) << 4;
    float4* d4 = (float4*)(dst + (size_t)(n0 + nl) * 512 + k0 + k16);
    const float4* s4 = (const float4*)&lt[nl][k16];
    d4[0] = s4[0];
    d4[1] = s4[1];
}

// ---------------------------------------------------------------- prep: biases (bq scaled) + Er f16
__global__ __launch_bounds__(256) void k_prep_small(const float* __restrict__ bq,
        const float* __restrict__ bk, const float* __restrict__ bv,
        const float* __restrict__ Er, float* __restrict__ bqkv,
        _Float16* __restrict__ Erh) {
    int idx = blockIdx.x * 256 + threadIdx.x;
    if (idx < NL * 1536) {
        int l = idx / 1536, j = idx % 1536;
        int which = j >> 9, jj = j & 511;
        float val = (which == 0) ? bq[l * 512 + jj] * QSC
                  : (which == 1) ? bk[l * 512 + jj] : bv[l * 512 + jj];
        bqkv[idx] = val;
    }
    int e = idx - NL * 1536;
    if (e >= 0 && e < NL * SEQ * DHD) Erh[e] = (_Float16)Er[e];
}

// ---------------------------------------------------------------- init: h = gelu(x*Winit + binit)
__global__ __launch_bounds__(256) void k_init(const float* __restrict__ x,
        const float* __restrict__ Wi, const float* __restrict__ bi,
        float* __restrict__ h, _Float16* __restrict__ hf) {
    int idx = blockIdx.x * 256 + threadIdx.x;
    int d = idx & (DIM - 1);
    int bs = idx >> 9;
    float val = gelu_exact(x[bs] * Wi[d] + bi[d]);
    h[idx] = val;
    hf[idx] = (_Float16)val;
}

// ---------------------------------------------------------------- f16 MFMA GEMM, 64x64 tile, BK=64, x32
template<int F16OUT>
__global__ __launch_bounds__(256) void k_gemm_mfma(const _Float16* __restrict__ A,
        const _Float16* __restrict__ Bt, const float* __restrict__ bias,
        _Float16* __restrict__ o16, float* __restrict__ o32) {
    __shared__ _Float16 As[64][72];
    __shared__ _Float16 Bs[64][72];
    const int tid = threadIdx.x;
    const int w = tid >> 6, lane = tid & 63;
    const int wm = (w & 1) << 5;       // 0 / 32
    const int wn = (w >> 1) << 5;      // 0 / 32
    const int nn = lane & 15, qd = lane >> 4;
    const int m0 = blockIdx.x << 6, n0 = blockIdx.y << 6;
    floatx4 acc[2][2] = {};
    for (int k0 = 0; k0 < 512; k0 += 64) {
        __syncthreads();
        #pragma unroll
        for (int r = 0; r < 2; r++) {
            int c = tid + (r << 8);
            int row = c >> 3, k8 = (c & 7) << 3;
            *(half8*)&As[row][k8] = *(const half8*)(A + (size_t)(m0 + row) * 512 + k0 + k8);
            *(half8*)&Bs[row][k8] = *(const half8*)(Bt + (size_t)(n0 + row) * 512 + k0 + k8);
        }
        __syncthreads();
        #pragma unroll
        for (int ks = 0; ks < 2; ks++) {
            half8 af[2], bf[2];
            #pragma unroll
            for (int t = 0; t < 2; t++) {
                af[t] = *(const half8*)&As[wm + (t << 4) + nn][(ks << 5) + (qd << 3)];
                bf[t] = *(const half8*)&Bs[wn + (t << 4) + nn][(ks << 5) + (qd << 3)];
            }
            #pragma unroll
            for (int ti = 0; ti < 2; ti++)
                #pragma unroll
                for (int tj = 0; tj < 2; tj++)
                    acc[ti][tj] = __builtin_amdgcn_mfma_f32_16x16x32_f16(
                            af[ti], bf[tj], acc[ti][tj], 0, 0, 0);
        }
    }
    float bv[2];
    #pragma unroll
    for (int tj = 0; tj < 2; tj++) bv[tj] = bias[n0 + wn + (tj << 4) + nn];
    #pragma unroll
    for (int ti = 0; ti < 2; ti++) {
        int rowg = m0 + wm + (ti << 4) + (qd << 2);
        #pragma unroll
        for (int tj = 0; tj < 2; tj++) {
            int colg = n0 + wn + (tj << 4) + nn;
            #pragma unroll
            for (int r = 0; r < 4; r++) {
                float val = acc[ti][tj][r] + bv[tj];
                if (F16OUT) {
                    int which = colg >> 9, ci = colg & 511;
                    o16[(size_t)which * 1048576 + (size_t)(rowg + r) * 512 + ci] = (_Float16)val;
                } else {
                    o32[(size_t)(rowg + r) * 512 + colg] = val;
                }
            }
        }
    }
}

// ---------------------------------------------------------------- MFMA causal rel-pos attention (f16)
// Split-K: grid (B*H, 16 qtiles, 2 splits). Block covers chunk range [c_lo, c_hi) of
// its q-tile; writes UNNORMALIZED O + (m, l) (exp2 domain). K/V staged per 256-row part.
__global__ __launch_bounds__(256, 4) void k_attn_mfma(const _Float16* __restrict__ q,
        const _Float16* __restrict__ k, const _Float16* __restrict__ v,
        const _Float16* __restrict__ Er, float* __restrict__ Osp,
        float* __restrict__ ml) {
    __shared__ _Float16 Ks[256][20];    // 10 KB
    __shared__ _Float16 Vts[16][264];   // 8.25 KB  (V^T)
    __shared__ float Rel[4][16][84];    // 21 KB    (per-wave skewed QEr^T)
    const int tid = threadIdx.x;
    const int wid = tid >> 6, lane = tid & 63;
    const int nn = lane & 15, a4 = (lane >> 4) << 2;
    const int b_ = blockIdx.x >> 5, h_ = blockIdx.x & 31;
    const int qt = blockIdx.y, sp = blockIdx.z;
    const int nch = qt + 1;
    const int hsp = (nch + 1) >> 1;                 // split0: [0,hsp) split1: [hsp,nch)
    const int c_lo = sp ? hsp : 0, c_hi = sp ? nch : hsp;
    const int r0 = qt << 6;
    const int s0w = r0 + (wid << 4);
    const int t_ = tid >> 2, c4 = (tid & 3) << 2;

    half4 qf = *(const half4*)(q + ((size_t)(b_ * SEQ + s0w + nn)) * DIM + h_ * DHD + a4);
    floatx4 O = {0.f, 0.f, 0.f, 0.f};
    float m = NEGF, lsum = 0.f;

    for (int cg = c_lo; cg < c_hi; cg += 4) {
        const int cge = (cg + 4 < c_hi) ? (cg + 4) : c_hi;
        __syncthreads();
        for (int g = 0; g < cge - cg; g++) {        // stage K + V^T rows
            int rl = (g << 6) + t_;
            size_t gb = ((size_t)(b_ * SEQ + (cg << 6) + rl)) * DIM + h_ * DHD + c4;
            *(half4*)&Ks[rl][c4] = *(const half4*)(k + gb);
            half4 vv4 = *(const half4*)(v + gb);
            Vts[c4 + 0][rl] = vv4.x;
            Vts[c4 + 1][rl] = vv4.y;
            Vts[c4 + 2][rl] = vv4.z;
            Vts[c4 + 3][rl] = vv4.w;
        }
        __syncthreads();
        for (int c = cg; c < cge; c++) {
            const int ct = c << 6;
            const int ctl = (c - cg) << 6;
            // QEr^T j-tiles -> Rel (Er direct from global; clamped rows masked later)
            const int jbw = 1008 - s0w + ct;
            #pragma unroll
            for (int jt = 0; jt < 5; jt++) {
                int j = jbw + (jt << 4) + nn;
                j = (j < SEQ - 1) ? j : (SEQ - 1);
                half4 ef = *(const half4*)(Er + (size_t)j * DHD + a4);
                floatx4 racc = {0.f, 0.f, 0.f, 0.f};
                racc = __builtin_amdgcn_mfma_f32_16x16x16f16(ef, qf, racc, 0, 0, 0);
                *(floatx4*)&Rel[wid][nn][(jt << 4) + a4] = racc;
            }
            // St = K·Q^T + Srel + causal mask
            float st[4][4];
            const bool diag = (ct == r0);
            #pragma unroll
            for (int tt = 0; tt < 4; tt++) {
                half4 kf = *(const half4*)&Ks[ctl + (tt << 4) + nn][a4];
                floatx4 sacc = {0.f, 0.f, 0.f, 0.f};
                sacc = __builtin_amdgcn_mfma_f32_16x16x16f16(kf, qf, sacc, 0, 0, 0);
                #pragma unroll
                for (int r = 0; r < 4; r++) {
                    int tl = (tt << 4) + a4 + r;
                    float sv = sacc[r] + Rel[wid][nn][15 - nn + tl];
                    if (diag && (tl > (wid << 4) + nn)) sv = NEGF;
                    st[tt][r] = sv;
                }
            }
            // online softmax (exp2 domain), state per s-col
            float cmax = NEGF;
            #pragma unroll
            for (int tt = 0; tt < 4; tt++)
                #pragma unroll
                for (int r = 0; r < 4; r++) cmax = fmaxf(cmax, st[tt][r]);
            cmax = fmaxf(cmax, __shfl_xor(cmax, 16));
            cmax = fmaxf(cmax, __shfl_xor(cmax, 32));
            float mnew = fmaxf(m, cmax);
            float alpha = exp2f(m - mnew);
            m = mnew;
            float csum = 0.f;
            half4 pf[4];
            #pragma unroll
            for (int tt = 0; tt < 4; tt++) {
                float p0e = exp2f(st[tt][0] - mnew);
                float p1e = exp2f(st[tt][1] - mnew);
                float p2e = exp2f(st[tt][2] - mnew);
                float p3e = exp2f(st[tt][3] - mnew);
                csum += (p0e + p1e) + (p2e + p3e);
                half4 ph4 = {(_Float16)p0e, (_Float16)p1e, (_Float16)p2e, (_Float16)p3e};
                pf[tt] = ph4;
            }
            csum += __shfl_xor(csum, 16);
            csum += __shfl_xor(csum, 32);
            lsum = lsum * alpha + csum;
            O[0] *= alpha; O[1] *= alpha; O[2] *= alpha; O[3] *= alpha;
            #pragma unroll
            for (int tt = 0; tt < 4; tt++) {
                half4 vf = *(const half4*)&Vts[nn][ctl + (tt << 4) + a4];
                O = __builtin_amdgcn_mfma_f32_16x16x16f16(vf, pf[tt], O, 0, 0, 0);
            }
        }
    }
    // epilogue: raw (unnormalized) O + per-row (m, l)
    float* op = Osp + (size_t)sp * 1048576
              + ((size_t)(b_ * SEQ + s0w + nn)) * DIM + h_ * DHD + a4;
    *(float4*)op = make_float4(O[0], O[1], O[2], O[3]);
    if (a4 == 0) {
        float2* mlp = (float2*)ml;
        mlp[((size_t)((sp * NB + b_) * NH + h_)) * SEQ + s0w + nn] = make_float2(m, lsum);
    }
}

// ---------------------------------------------------------------- merge 2 attention splits -> ah f16
__global__ __launch_bounds__(256) void k_attn_merge(const float* __restrict__ Osp,
        const float* __restrict__ ml, _Float16* __restrict__ ah) {
    int idx = blockIdx.x * 256 + threadIdx.x;       // 262144 total
    int d4g = (idx & 127) << 2;
    int row = idx >> 7;                              // b*1024 + s
    int b = row >> 10, s = row & 1023, h = d4g >> 4;
    const float2* mlp = (const float2*)ml;
    float2 ml0 = mlp[((size_t)((0 * NB + b) * NH + h)) * SEQ + s];
    float2 ml1 = mlp[((size_t)((1 * NB + b) * NH + h)) * SEQ + s];
    float ms = fmaxf(ml0.x, ml1.x);
    float w0 = exp2f(ml0.x - ms), w1 = exp2f(ml1.x - ms);
    float li = ml0.y * w0 + ml1.y * w1;
    float inv = 1.0f / li;
    float4 O0 = *(const float4*)(Osp + (size_t)row * 512 + d4g);
    float4 O1 = *(const float4*)(Osp + 1048576 + (size_t)row * 512 + d4g);
    half4 r = { (_Float16)((O0.x * w0 + O1.x * w1) * inv),
                (_Float16)((O0.y * w0 + O1.y * w1) * inv),
                (_Float16)((O0.z * w0 + O1.z * w1) * inv),
                (_Float16)((O0.w * w0 + O1.w * w1) * inv) };
    *(half4*)(ah + (size_t)row * 512 + d4g) = r;
}

// ---------------------------------------------------------------- h += gelu(LN(y)); also h f16 copy
__global__ __launch_bounds__(256) void k_ln_gelu_res(const float* __restrict__ y,
        const float* __restrict__ gam, const float* __restrict__ bet,
        float* __restrict__ h, _Float16* __restrict__ hf) {
    __shared__ float red[8];
    int row = blockIdx.x, tid = threadIdx.x;
    const float* yr = y + (size_t)row * DIM;
    float v0 = yr[tid], v1 = yr[tid + 256];
    float sum = v0 + v1, sq = v0 * v0 + v1 * v1;
    #pragma unroll
    for (int off = 32; off > 0; off >>= 1) {
        sum += __shfl_down(sum, off);
        sq  += __shfl_down(sq, off);
    }
    if ((tid & 63) == 0) { red[tid >> 6] = sum; red[4 + (tid >> 6)] = sq; }
    __syncthreads();
    float ts = red[0] + red[1] + red[2] + red[3];
    float tq = red[4] + red[5] + red[6] + red[7];
    float mu = ts * (1.0f / DIM);
    float var = tq * (1.0f / DIM) - mu * mu;
    float rs = rsqrtf(var + LN_EPS);
    float z0 = (v0 - mu) * rs * gam[tid] + bet[tid];
    float z1 = (v1 - mu) * rs * gam[tid + 256] + bet[tid + 256];
    size_t base = (size_t)row * DIM;
    float nh0 = h[base + tid] + gelu_exact(z0);
    float nh1 = h[base + tid + 256] + gelu_exact(z1);
    h[base + tid] = nh0;
    h[base + tid + 256] = nh1;
    hf[base + tid] = (_Float16)nh0;
    hf[base + tid + 256] = (_Float16)nh1;
}

// ---------------------------------------------------------------- final sum over S, dot with Wout
__global__ __launch_bounds__(256) void k_colsum(const float* __restrict__ h,
        float* __restrict__ partial) {
    int bt = blockIdx.x;
    int b_ = bt >> 4, t = bt & 15;
    int tid = threadIdx.x;
    #pragma unroll
    for (int half = 0; half < 2; half++) {
        int d = half * 256 + tid;
        float acc = 0.f;
        for (int i = 0; i < 64; i++)
            acc += h[((size_t)(b_ * SEQ + t * 64 + i)) * DIM + d];
        partial[(size_t)bt * DIM + d] = acc;
    }
}

__global__ __launch_bounds__(256) void k_final(const float* __restrict__ partial,
        const float* __restrict__ Wout, float* __restrict__ out) {
    __shared__ float red[4][2];
    int tid = threadIdx.x;
    float acc0 = 0.f, acc1 = 0.f;
    #pragma unroll
    for (int half = 0; half < 2; half++) {
        int d = half * 256 + tid;
        float w = Wout[d];
        float s0 = 0.f, s1 = 0.f;
        for (int t = 0; t < 16; t++) {
            s0 += partial[t * DIM + d];
            s1 += partial[(16 + t) * DIM + d];
        }
        acc0 += s0 * w;
        acc1 += s1 * w;
    }
    #pragma unroll
    for (int off = 32; off > 0; off >>= 1) {
        acc0 += __shfl_down(acc0, off);
        acc1 += __shfl_down(acc1, off);
    }
    if ((tid & 63) == 0) { red[tid >> 6][0] = acc0; red[tid >> 6][1] = acc1; }
    __syncthreads();
    if (tid == 0) {
        out[0] = red[0][0] + red[1][0] + red[2][0] + red[3][0];
        out[1] = red[0][1] + red[1][1] + red[2][1] + red[3][1];
    }
}

extern "C" void kernel_launch(void* const* d_in, const int* in_sizes, int n_in,
                              void* d_out, int out_size, void* d_ws, size_t ws_size,
                              hipStream_t stream) {
    const float* x    = (const float*)d_in[0];
    const float* Wi   = (const float*)d_in[1];
    const float* bi   = (const float*)d_in[2];
    const float* Wq   = (const float*)d_in[3];
    const float* bq   = (const float*)d_in[4];
    const float* Wk   = (const float*)d_in[5];
    const float* bk   = (const float*)d_in[6];
    const float* Wv   = (const float*)d_in[7];
    const float* bv   = (const float*)d_in[8];
    const float* Er   = (const float*)d_in[9];
    const float* Wlin = (const float*)d_in[10];
    const float* blin = (const float*)d_in[11];
    const float* lng  = (const float*)d_in[12];
    const float* lnb  = (const float*)d_in[13];
    const float* Wout = (const float*)d_in[14];
    float* out = (float*)d_out;

    float* ws = (float*)d_ws;
    const size_t N1 = 1048576;                       // B*S*D
    float*     h     = ws;                           // [0, 1N)
    _Float16*  hf    = (_Float16*)(ws + N1);         // [1N, 1.5N)
    _Float16*  qh    = (_Float16*)(ws + N1 + N1/2);  // [1.5N, 3N): q,k,v f16
    float*     y     = ws + 3 * N1;                  // [3N, 4N)
    _Float16*  ah    = (_Float16*)(ws + 4 * N1);     // [4N, 4.5N)
    _Float16*  Wqkvt = (_Float16*)(ws + 4 * N1 + N1/2);  // [4.5N, 6N)
    _Float16*  Wlint = (_Float16*)(ws + 6 * N1);         // [6N, 6.5N)
    float*     bqkv  = ws + 6 * N1 + N1/2;               // 6144 floats
    _Float16*  Erh   = (_Float16*)(ws + 6 * N1 + N1/2 + 8192);  // 65536 f16
    float*     Osp   = ws + 7 * N1;                  // [7N, 9N): 2 splits f32
    float*     ml    = ws + 9 * N1;                  // 262144 floats (2*2*32*1024 float2)
    float*     pa    = ws + 9 * N1 + 262144 + 64;

    k_prep_w<<<dim3(8, 8, 16), dim3(256), 0, stream>>>(Wq, Wk, Wv, Wlin, Wqkvt, Wlint);
    k_prep_small<<<dim3(280), dim3(256), 0, stream>>>(bq, bk, bv, Er, bqkv, Erh);
    k_init<<<dim3(4096), dim3(256), 0, stream>>>(x, Wi, bi, h, hf);
    for (int l = 0; l < NL; l++) {
        k_gemm_mfma<1><<<dim3(32, 24), dim3(256), 0, stream>>>(
                hf, Wqkvt + (size_t)l * 786432, bqkv + l * 1536, qh, nullptr);
        k_attn_mfma<<<dim3(NB * NH, 16, 2), dim3(256), 0, stream>>>(
                qh, qh + 1048576, qh + 2097152, Erh + (size_t)l * 16384, Osp, ml);
        k_attn_merge<<<dim3(1024), dim3(256), 0, stream>>>(Osp, ml, ah);
        k_gemm_mfma<0><<<dim3(32, 8), dim3(256), 0, stream>>>(
                ah, Wlint + (size_t)l * 262144, blin + l * 512, nullptr, y);
        k_ln_gelu_res<<<dim3(NB * SEQ), dim3(256), 0, stream>>>(
                y, lng + l * 512, lnb + l * 512, h, hf);
    }
    k_colsum<<<dim3(32), dim3(256), 0, stream>>>(h, pa);
    k_final<<<dim3(1), dim3(256), 0, stream>>>(pa, Wout, out);
}